// Round 9
// baseline (39.892 us; speedup 1.0000x reference)
//
#include <hip/hip_runtime.h>

// SplineConv: out[n, o, i] = sum_{a,b in 0..2} wx[n,a]*wy[n,b] * C[o,i,kx-2+a,ky-2+b]
// N=32768 points, C is (32,32,7,7) f32, out is (N,32,32) f32 = 128 MiB (HBM-write-bound).
//
// Round-8 = round-6 with the nontemporal-store type fixed (clang ext_vector,
// HIP float2 is rejected by the builtin):
//  - NO record prefetch (TLP at 4 waves/SIMD hides the ~120cy LDS broadcast).
//  - __launch_bounds__(256, 4): cap VGPR at 128 -> 4 blocks/CU, no straggler cohort.
//  - nontemporal 8B output stores (write-once stream; keep L2 for C).
// Window offset is READFIRSTLANE'd so the 25-way switch is a scalar jump table
// (vector switch gets if-converted to ~500 predicated VALU ops/point).

#define NPTS   32768
#define DIM    1024        // 32*32 channels
#define PPB    64          // points per block
#define RSTR   12          // floats per LDS record (48B, 16B-aligned)

typedef float f32x2 __attribute__((ext_vector_type(2)));

__device__ __forceinline__ float safe_div(float n, float d) {
    return (d == 0.0f) ? n : (n / d);
}

__device__ __forceinline__ void span_weights(float v, const float* __restrict__ T,
                                             int& k, float& w0, float& w1, float& w2) {
    float t3 = T[3], t4 = T[4], t5 = T[5], t6 = T[6];
    k = 2 + (v >= t3) + (v >= t4) + (v >= t5) + (v >= t6);
    float Tm1 = T[k - 1], T0 = T[k], Tp1 = T[k + 1], Tp2 = T[k + 2];
    float a10 = safe_div(v - Tm1, Tp1 - Tm1);
    float a11 = safe_div(v - T0,  Tp2 - T0);
    float a21 = safe_div(v - T0,  Tp1 - T0);
    w0 = (1.0f - a21) * (1.0f - a10);
    w1 = (1.0f - a21) * a10 + a21 * (1.0f - a11);
    w2 = a21 * a11;
}

__global__ __launch_bounds__(256, 4) void spline_main_kernel(
    const float* __restrict__ C,
    const float* __restrict__ xy,
    const float* __restrict__ Tx,
    const float* __restrict__ Ty,
    float* __restrict__ out)
{
    __shared__ float recs[PPB][RSTR];

    const int t     = threadIdx.x;
    const int g     = blockIdx.x & 1;          // channel half: 0 or 1
    const int chunk = blockIdx.x >> 1;
    const int p0    = chunk * PPB;
    const int ch    = g * 512 + t * 2;         // this thread's first channel

    // --- Wave 0: compute this block's 64 point-records into LDS -------------
    if (t < PPB) {
        const int p = p0 + t;
        const float2 pt = ((const float2*)xy)[p];
        int kx, ky;
        float wx0, wx1, wx2, wy0, wy1, wy2;
        span_weights(pt.x, Tx, kx, wx0, wx1, wx2);
        span_weights(pt.y, Ty, ky, wy0, wy1, wy2);
        float* r = recs[t];
        r[0] = wx0 * wy0;  r[1] = wx0 * wy1;  r[2] = wx0 * wy2;
        r[3] = wx1 * wy0;  r[4] = wx1 * wy1;  r[5] = wx1 * wy2;
        r[6] = wx2 * wy0;  r[7] = wx2 * wy1;  r[8] = wx2 * wy2;
        r[9] = __int_as_float((kx - 2) * 7 + (ky - 2));
        r[10] = 0.0f; r[11] = 0.0f;
    }

    // --- All threads: two channel rows -> registers, PLANAR ------------------
    // c[0..48] = C row ch, c[49..97] = C row ch+1 (ch even -> 8B-aligned).
    float c[98];
    {
        const float2* src = (const float2*)(C + (size_t)ch * 49);
#pragma unroll
        for (int q = 0; q < 49; ++q) {
            float2 v = src[q];
            c[2 * q]     = v.x;     // linear fill: c[i] = C[ch*49 + i]
            c[2 * q + 1] = v.y;
        }
    }

    __syncthreads();

    f32x2* outp = (f32x2*)(out + (size_t)p0 * DIM + ch);

    for (int i = 0; i < PPB; ++i) {
        // Uniform-address LDS reads -> broadcast. No prefetch: 4 waves/SIMD TLP
        // covers the LDS latency; saves ~19 VGPRs vs double-buffering.
        const int   off = __builtin_amdgcn_readfirstlane(__float_as_int(recs[i][9]));
        const float4 wA = *(const float4*)(&recs[i][0]);
        const float4 wB = *(const float4*)(&recs[i][4]);
        const float  w8 = recs[i][8];

        float s0, s1;
        switch (off) {
#define TERM(q, dq, w)                                      \
            s0 = fmaf(w, c[(q) + (dq)],      s0);           \
            s1 = fmaf(w, c[49 + (q) + (dq)], s1);
#define CASE_IJ(i_, j_)                                     \
        case ((i_) * 7 + (j_)): {                           \
            const int q = (i_) * 7 + (j_);                  \
            s0 = wA.x * c[q];                               \
            s1 = wA.x * c[49 + q];                          \
            TERM(q, 1,  wA.y)  TERM(q, 2,  wA.z)            \
            TERM(q, 7,  wA.w)  TERM(q, 8,  wB.x)  TERM(q, 9,  wB.y) \
            TERM(q, 14, wB.z)  TERM(q, 15, wB.w)  TERM(q, 16, w8)   \
        } break;
        CASE_IJ(0, 0) CASE_IJ(0, 1) CASE_IJ(0, 2) CASE_IJ(0, 3) CASE_IJ(0, 4)
        CASE_IJ(1, 0) CASE_IJ(1, 1) CASE_IJ(1, 2) CASE_IJ(1, 3) CASE_IJ(1, 4)
        CASE_IJ(2, 0) CASE_IJ(2, 1) CASE_IJ(2, 2) CASE_IJ(2, 3) CASE_IJ(2, 4)
        CASE_IJ(3, 0) CASE_IJ(3, 1) CASE_IJ(3, 2) CASE_IJ(3, 3) CASE_IJ(3, 4)
        CASE_IJ(4, 0) CASE_IJ(4, 1) CASE_IJ(4, 2) CASE_IJ(4, 3) CASE_IJ(4, 4)
#undef CASE_IJ
#undef TERM
        default: s0 = 0.0f; s1 = 0.0f; break;
        }

        // Streaming 8B/lane coalesced nontemporal store.
        f32x2 v2; v2.x = s0; v2.y = s1;
        __builtin_nontemporal_store(v2, outp);
        outp += DIM / 2;
    }
}

extern "C" void kernel_launch(void* const* d_in, const int* in_sizes, int n_in,
                              void* d_out, int out_size, void* d_ws, size_t ws_size,
                              hipStream_t stream) {
    const float* xy = (const float*)d_in[0];
    const float* Tx = (const float*)d_in[1];
    const float* Ty = (const float*)d_in[2];
    const float* C  = (const float*)d_in[3];
    float* out = (float*)d_out;

    spline_main_kernel<<<2 * (NPTS / PPB), 256, 0, stream>>>(C, xy, Tx, Ty, out);
}

// Round 10
// 39.769 us; speedup vs baseline: 1.0031x; 1.0031x over previous
//
#include <hip/hip_runtime.h>

// SplineConv: out[n, o, i] = sum_{a,b in 0..2} wx[n,a]*wy[n,b] * C[o,i,kx-2+a,ky-2+b]
// N=32768 points, C is (32,32,7,7) f32, out is (N,32,32) f32 = 128 MiB (HBM-write-bound).
//
// Round-10 = discriminating experiment: R5's prefetch (OFF-WORD ONLY, ~9 fewer
// live VGPRs than R5's full record double-buffer) + launch_bounds(256,4) + nt.
//  - off[i+1] prefetched -> the scalar jump for each point never waits on LDS;
//    weight ds_reads issue before the branch, latency hidden by TLP + FMA stream.
//  - launch_bounds(256,4): cap VGPR at 128 -> 4 blocks/CU (kill the 256-block
//    straggler cohort if R5 was at 3 blocks/CU).
//  - nontemporal 8B output stores.
// Window offset is READFIRSTLANE'd so the 25-way switch is a scalar jump table
// (vector switch gets if-converted to ~500 predicated VALU ops/point).

#define NPTS   32768
#define DIM    1024        // 32*32 channels
#define PPB    64          // points per block
#define RSTR   12          // floats per LDS record (48B, 16B-aligned)

typedef float f32x2 __attribute__((ext_vector_type(2)));

__device__ __forceinline__ float safe_div(float n, float d) {
    return (d == 0.0f) ? n : (n / d);
}

__device__ __forceinline__ void span_weights(float v, const float* __restrict__ T,
                                             int& k, float& w0, float& w1, float& w2) {
    float t3 = T[3], t4 = T[4], t5 = T[5], t6 = T[6];
    k = 2 + (v >= t3) + (v >= t4) + (v >= t5) + (v >= t6);
    float Tm1 = T[k - 1], T0 = T[k], Tp1 = T[k + 1], Tp2 = T[k + 2];
    float a10 = safe_div(v - Tm1, Tp1 - Tm1);
    float a11 = safe_div(v - T0,  Tp2 - T0);
    float a21 = safe_div(v - T0,  Tp1 - T0);
    w0 = (1.0f - a21) * (1.0f - a10);
    w1 = (1.0f - a21) * a10 + a21 * (1.0f - a11);
    w2 = a21 * a11;
}

__global__ __launch_bounds__(256, 4) void spline_main_kernel(
    const float* __restrict__ C,
    const float* __restrict__ xy,
    const float* __restrict__ Tx,
    const float* __restrict__ Ty,
    float* __restrict__ out)
{
    __shared__ float recs[PPB][RSTR];

    const int t     = threadIdx.x;
    const int g     = blockIdx.x & 1;          // channel half: 0 or 1
    const int chunk = blockIdx.x >> 1;
    const int p0    = chunk * PPB;
    const int ch    = g * 512 + t * 2;         // this thread's first channel

    // --- Wave 0: compute this block's 64 point-records into LDS -------------
    if (t < PPB) {
        const int p = p0 + t;
        const float2 pt = ((const float2*)xy)[p];
        int kx, ky;
        float wx0, wx1, wx2, wy0, wy1, wy2;
        span_weights(pt.x, Tx, kx, wx0, wx1, wx2);
        span_weights(pt.y, Ty, ky, wy0, wy1, wy2);
        float* r = recs[t];
        r[0] = wx0 * wy0;  r[1] = wx0 * wy1;  r[2] = wx0 * wy2;
        r[3] = wx1 * wy0;  r[4] = wx1 * wy1;  r[5] = wx1 * wy2;
        r[6] = wx2 * wy0;  r[7] = wx2 * wy1;  r[8] = wx2 * wy2;
        r[9] = __int_as_float((kx - 2) * 7 + (ky - 2));
        r[10] = 0.0f; r[11] = 0.0f;
    }

    // --- All threads: two channel rows -> registers, PLANAR ------------------
    // c[0..48] = C row ch, c[49..97] = C row ch+1 (ch even -> 8B-aligned).
    float c[98];
    {
        const float2* src = (const float2*)(C + (size_t)ch * 49);
#pragma unroll
        for (int q = 0; q < 49; ++q) {
            float2 v = src[q];
            c[2 * q]     = v.x;     // linear fill: c[i] = C[ch*49 + i]
            c[2 * q + 1] = v.y;
        }
    }

    __syncthreads();

    f32x2* outp = (f32x2*)(out + (size_t)p0 * DIM + ch);

    // Prefetch the first point's offset word only (1 VGPR of state).
    float offw = recs[0][9];

    for (int i = 0; i < PPB; ++i) {
        const int off = __builtin_amdgcn_readfirstlane(__float_as_int(offw));

        // Prefetch next offset word (branchless clamp; hides under this body).
        const int j = (i + 1 < PPB) ? (i + 1) : i;
        offw = recs[j][9];

        // Weight reads issue before the branch; latency covered by TLP + FMAs.
        const float4 wA = *(const float4*)(&recs[i][0]);
        const float4 wB = *(const float4*)(&recs[i][4]);
        const float  w8 = recs[i][8];

        float s0, s1;
        switch (off) {
#define TERM(q, dq, w)                                      \
            s0 = fmaf(w, c[(q) + (dq)],      s0);           \
            s1 = fmaf(w, c[49 + (q) + (dq)], s1);
#define CASE_IJ(i_, j_)                                     \
        case ((i_) * 7 + (j_)): {                           \
            const int q = (i_) * 7 + (j_);                  \
            s0 = wA.x * c[q];                               \
            s1 = wA.x * c[49 + q];                          \
            TERM(q, 1,  wA.y)  TERM(q, 2,  wA.z)            \
            TERM(q, 7,  wA.w)  TERM(q, 8,  wB.x)  TERM(q, 9,  wB.y) \
            TERM(q, 14, wB.z)  TERM(q, 15, wB.w)  TERM(q, 16, w8)   \
        } break;
        CASE_IJ(0, 0) CASE_IJ(0, 1) CASE_IJ(0, 2) CASE_IJ(0, 3) CASE_IJ(0, 4)
        CASE_IJ(1, 0) CASE_IJ(1, 1) CASE_IJ(1, 2) CASE_IJ(1, 3) CASE_IJ(1, 4)
        CASE_IJ(2, 0) CASE_IJ(2, 1) CASE_IJ(2, 2) CASE_IJ(2, 3) CASE_IJ(2, 4)
        CASE_IJ(3, 0) CASE_IJ(3, 1) CASE_IJ(3, 2) CASE_IJ(3, 3) CASE_IJ(3, 4)
        CASE_IJ(4, 0) CASE_IJ(4, 1) CASE_IJ(4, 2) CASE_IJ(4, 3) CASE_IJ(4, 4)
#undef CASE_IJ
#undef TERM
        default: s0 = 0.0f; s1 = 0.0f; break;
        }

        // Streaming 8B/lane coalesced nontemporal store.
        f32x2 v2; v2.x = s0; v2.y = s1;
        __builtin_nontemporal_store(v2, outp);
        outp += DIM / 2;
    }
}

extern "C" void kernel_launch(void* const* d_in, const int* in_sizes, int n_in,
                              void* d_out, int out_size, void* d_ws, size_t ws_size,
                              hipStream_t stream) {
    const float* xy = (const float*)d_in[0];
    const float* Tx = (const float*)d_in[1];
    const float* Ty = (const float*)d_in[2];
    const float* C  = (const float*)d_in[3];
    float* out = (float*)d_out;

    spline_main_kernel<<<2 * (NPTS / PPB), 256, 0, stream>>>(C, xy, Tx, Ty, out);
}